// Round 14
// baseline (191.722 us; speedup 1.0000x reference)
//
#include <hip/hip_runtime.h>
#include <hip/hip_fp16.h>
#include <stdint.h>

typedef __attribute__((ext_vector_type(4))) float f32x4;
typedef __attribute__((ext_vector_type(8))) short short8;

__device__ __forceinline__ unsigned short f2bf(float f) {
  unsigned int b = __float_as_uint(f);
  b = b + 0x7FFFu + ((b >> 16) & 1u);   // RNE
  return (unsigned short)(b >> 16);
}

#define CE(a, b) { float _lo = fminf((a), (b)), _hi = fmaxf((a), (b)); (a) = _lo; (b) = _hi; }

// Batcher odd-even merge of two ascending sorted 4-lists (x[0..3], x[4..7]) -> sorted 8
__device__ __forceinline__ void merge8(float x[8]) {
  CE(x[0], x[4]); CE(x[1], x[5]); CE(x[2], x[6]); CE(x[3], x[7]);
  CE(x[2], x[4]); CE(x[3], x[5]);
  CE(x[1], x[2]); CE(x[3], x[4]); CE(x[5], x[6]);
}

// ---------------------------------------------------------------------------
// Fused prep kernel: blocks 0..4095 = per-row NF4 quant+dequant of W -> qb,
//                    blocks 4096..8191 = x fp32 -> bf16 cvt
// ---------------------------------------------------------------------------
__global__ __launch_bounds__(256) void prep_kernel(const float* __restrict__ x,
                                                   const float* __restrict__ W,
                                                   const float* __restrict__ lut,
                                                   unsigned short* __restrict__ xb,
                                                   unsigned short* __restrict__ qb) {
  const int tid = threadIdx.x;

  if (blockIdx.x >= 4096) {
    // ---- cvt path ----
    int b = blockIdx.x - 4096;
    int base = b * 1024 + tid;   // float4 index
#pragma unroll
    for (int it = 0; it < 4; ++it) {
      int i = base + it * 256;
      f32x4 v = ((const f32x4*)x)[i];
      ushort4 u;
      u.x = f2bf(v[0]); u.y = f2bf(v[1]); u.z = f2bf(v[2]); u.w = f2bf(v[3]);
      ((ushort4*)xb)[i] = u;
    }
    return;
  }

  // ---- quant path ----
  const int C = 4096;
  const int row = blockIdx.x;
  const int lane = tid & 63;
  const int wv = tid >> 6;

  __shared__ float s_luth[16];   // fp16-rounded poles (dequant values)
  __shared__ float s_mid[15];    // decision midpoints on fp32 poles
  __shared__ float s_red[4][8];
  __shared__ float s_par[4];

  if (tid < 16) {
    float f = lut[tid];
    s_luth[tid] = __half2float(__float2half(f));  // .half() per reference
  }
  if (tid < 15) s_mid[tid] = 0.5f * (lut[tid] + lut[tid + 1]);

  const f32x4* Wp = (const f32x4*)(W + (size_t)row * C);
  f32x4 v[4];
#pragma unroll
  for (int i = 0; i < 4; ++i) v[i] = Wp[i * 256 + tid];

  // per-thread bottom-4 (ascending) and top-4 (ascending)
  float bot[4] = {__builtin_inff(), __builtin_inff(), __builtin_inff(), __builtin_inff()};
  float top[4] = {-__builtin_inff(), -__builtin_inff(), -__builtin_inff(), -__builtin_inff()};
#pragma unroll
  for (int i = 0; i < 4; ++i) {
#pragma unroll
    for (int j = 0; j < 4; ++j) {
      float f = v[i][j];
      bot[3] = fminf(bot[3], f); CE(bot[2], bot[3]); CE(bot[1], bot[2]); CE(bot[0], bot[1]);
      top[0] = fmaxf(top[0], f); CE(top[0], top[1]); CE(top[1], top[2]); CE(top[2], top[3]);
    }
  }

#pragma unroll
  for (int d = 1; d < 64; d <<= 1) {
    float xx[8];
#pragma unroll
    for (int j = 0; j < 4; ++j) { xx[j] = bot[j]; xx[4 + j] = __shfl_xor(bot[j], d); }
    merge8(xx);
#pragma unroll
    for (int j = 0; j < 4; ++j) bot[j] = xx[j];
#pragma unroll
    for (int j = 0; j < 4; ++j) { xx[j] = top[j]; xx[4 + j] = __shfl_xor(top[j], d); }
    merge8(xx);
#pragma unroll
    for (int j = 0; j < 4; ++j) top[j] = xx[4 + j];
  }

  if (lane == 0) {
#pragma unroll
    for (int j = 0; j < 4; ++j) { s_red[wv][j] = bot[j]; s_red[wv][4 + j] = top[j]; }
  }
  __syncthreads();

  if (tid == 0) {
    float a[8], b[8], m[8];
#pragma unroll
    for (int j = 0; j < 4; ++j) { a[j] = s_red[0][j]; a[4 + j] = s_red[1][j]; }
    merge8(a);
#pragma unroll
    for (int j = 0; j < 4; ++j) { b[j] = s_red[2][j]; b[4 + j] = s_red[3][j]; }
    merge8(b);
#pragma unroll
    for (int j = 0; j < 4; ++j) { m[j] = a[j]; m[4 + j] = b[j]; }
    merge8(m);
    float lower = m[2] + 0.0475f * (m[3] - m[2]);   // quantile 0.0005 -> idx 2.0475
#pragma unroll
    for (int j = 0; j < 4; ++j) { a[j] = s_red[0][4 + j]; a[4 + j] = s_red[1][4 + j]; }
    merge8(a);
#pragma unroll
    for (int j = 0; j < 4; ++j) { b[j] = s_red[2][4 + j]; b[4 + j] = s_red[3][4 + j]; }
    merge8(b);
#pragma unroll
    for (int j = 0; j < 4; ++j) { m[j] = a[4 + j]; m[4 + j] = b[4 + j]; }
    merge8(m);
    float upper = m[4] + 0.9525f * (m[5] - m[4]);   // quantile 0.9995 -> idx 4092.9525
    s_par[0] = lower; s_par[1] = upper;
  }
  __syncthreads();

  float lower = s_par[0], upper = s_par[1];

  float mn = __builtin_inff(), mx = -__builtin_inff();
#pragma unroll
  for (int i = 0; i < 4; ++i) {
#pragma unroll
    for (int j = 0; j < 4; ++j) {
      float f = v[i][j];
      bool outl = (f <= lower) || (f >= upper);
      if (!outl) { mn = fminf(mn, f); mx = fmaxf(mx, f); }
    }
  }
#pragma unroll
  for (int d = 1; d < 64; d <<= 1) {
    mn = fminf(mn, __shfl_xor(mn, d));
    mx = fmaxf(mx, __shfl_xor(mx, d));
  }
  if (lane == 0) { s_red[wv][0] = mn; s_red[wv][1] = mx; }
  __syncthreads();
  if (tid == 0) {
    float tmn = fminf(fminf(s_red[0][0], s_red[1][0]), fminf(s_red[2][0], s_red[3][0]));
    float tmx = fmaxf(fmaxf(s_red[0][1], s_red[1][1]), fmaxf(s_red[2][1], s_red[3][1]));
    s_par[2] = (tmx + tmn) * 0.5f;   // offset
    s_par[3] = (tmx - tmn) * 0.5f;   // rangeval
  }
  __syncthreads();
  float offset = s_par[2], range = s_par[3];
  float invr = 1.0f / range;

  unsigned short* outr = qb + (size_t)row * C;
#pragma unroll
  for (int i = 0; i < 4; ++i) {
    ushort4 o;
    unsigned short os[4];
#pragma unroll
    for (int j = 0; j < 4; ++j) {
      float f = v[i][j];
      bool outl = (f <= lower) || (f >= upper);
      float q;
      if (outl) {
        q = f;  // Q=0 pole -> weight passes through
      } else {
        // nearest pole via branchless binary search on midpoints.
        // strict '>' keeps the LOWER index on exact ties == argmin semantics.
        float ws = (f - offset) * invr;
        int bi = (ws > s_mid[7]) ? 8 : 0;
        bi += (ws > s_mid[bi + 3]) ? 4 : 0;
        bi += (ws > s_mid[bi + 1]) ? 2 : 0;
        bi += (ws > s_mid[bi]) ? 1 : 0;
        q = s_luth[bi] * range + offset;
      }
      if (!isfinite(q)) q = 0.0f;
      os[j] = f2bf(q);
    }
    o.x = os[0]; o.y = os[1]; o.z = os[2]; o.w = os[3];
    ((ushort4*)outr)[i * 256 + tid] = o;
  }
}

// ---------------------------------------------------------------------------
// GEMM round 14 = round 11/13 main loop (measured optimum: 114.7us, MfmaUtil
// 54%, conflicts 0) + LDS-transposed vectorized epilogue:
//   old: 128x global_store_dword/thread (4x64B segments per wave-instr)
//   new: per 32-row chunk: acc -> LDS [32 rows x 272B padded] -> ds_read_b128
//        -> 32x global_store_dwordx4/thread (4x256B contiguous per wave-instr)
//   272B stride: write banks = (row*4+col)%32 -> 2-way; read banks 2-way (free).
//   Per-wave private 8704B slice (waves 0-3 in sA, 4-7 in sB); no barriers.
//   VM0+BAR before epilogue drains tail-clamped stage loads still writing LDS.
// ---------------------------------------------------------------------------
#define GK 4096

__device__ __forceinline__ void gload16(const void* gp, void* lp) {
  __builtin_amdgcn_global_load_lds(
      (const __attribute__((address_space(1))) unsigned int*)(uintptr_t)gp,
      (__attribute__((address_space(3))) unsigned int*)(unsigned int)(uintptr_t)lp,
      16, 0, 0);
}

#define BAR()    __builtin_amdgcn_s_barrier()
#define VM0()    asm volatile("s_waitcnt vmcnt(0)" ::: "memory")
#define VM2()    asm volatile("s_waitcnt vmcnt(2)" ::: "memory")
#define VM6()    asm volatile("s_waitcnt vmcnt(6)" ::: "memory")
#define LGKM0()  asm volatile("s_waitcnt lgkmcnt(0)" ::: "memory")
#define PRIO1()  __builtin_amdgcn_s_setprio(1)
#define PRIO0()  __builtin_amdgcn_s_setprio(0)

// frag-read address helper (subtiled st_16x32 layout, conflicts==0)
#define ARD(buf, m, kh)  (*(const short8*)((buf) + (m) * 2048 + (kh) * 1024 + fr * 64 + cA))

__global__ __launch_bounds__(512, 2) void gemm_bt(const unsigned short* __restrict__ A,
                                                  const unsigned short* __restrict__ B,
                                                  float* __restrict__ C) {
  // [kbuf][half][16KB half-tile] ; total 128 KiB
  __shared__ __align__(16) unsigned short sA[2][2][8192];
  __shared__ __align__(16) unsigned short sB[2][2][8192];

  const int tid = threadIdx.x;
  const int lane = tid & 63;
  const int wv = tid >> 6;
  const int wm = wv >> 2, wn = wv & 3;       // 2 x 4 wave grid; wave tile 128 x 64
  const int fr = lane & 15, fk = lane >> 4;

  // XCD-aware swizzle: 256 blocks, 256 % 8 == 0 -> bijective
  int bi = blockIdx.x;
  int swz = (bi & 7) * 32 + (bi >> 3);
  int brow = swz >> 4, bcol = swz & 15;

  const unsigned short* Abase = A + (size_t)brow * 256 * GK;
  const unsigned short* Bbase = B + (size_t)bcol * 256 * GK;

  // read-side swizzled column byte within 64B row: fk*16 ^ (row-bit-3 << 5)
  const int cA = (fk * 16) ^ ((fr & 8) << 2);

  // stage source permutation (verified bijective): LDS bytes [wv*1024+l*8192+lane*16)
  // hold global (row = l*64 + (wv>>1)*16 + (lane>>2),
  //              kbyte = (wv&1)*64 + ((lane&3)*16 ^ (lane&32 ? 32 : 0)))
  const int srow = (wv >> 1) * 16 + (lane >> 2);                 // + l*64
  const int skelt = ((wv & 1) * 64 + (((lane & 3) * 16) ^ ((lane & 32) ? 32 : 0))) >> 1;

  auto stage = [&](const unsigned short* gb, unsigned short* lb, int h, int kt) {
    const unsigned short* g = gb + ((size_t)h * 128) * GK + kt * 64 + skelt;
    char* lc = (char*)lb + wv * 1024 + lane * 16;
#pragma unroll
    for (int l = 0; l < 2; ++l)
      gload16(g + (size_t)(l * 64 + srow) * GK, lc + l * 8192);
  };

  f32x4 acc[8][4];
#pragma unroll
  for (int m = 0; m < 8; ++m)
#pragma unroll
    for (int n = 0; n < 4; ++n) acc[m][n] = (f32x4){0.f, 0.f, 0.f, 0.f};

  const int nsub = (wn & 1) * 4;       // B subtile-row base within half

  // ---- prologue: A(0)h0,h1, B(0)h0,h1 [kbuf0] + B(1)h0,h1, A(1)h0 [kbuf1]
  stage(Abase, &sA[0][0][0], 0, 0);
  stage(Abase, &sA[0][1][0], 1, 0);
  stage(Bbase, &sB[0][0][0], 0, 0);
  stage(Bbase, &sB[0][1][0], 1, 0);
  stage(Bbase, &sB[1][0][0], 0, 1);
  stage(Bbase, &sB[1][1][0], 1, 1);
  stage(Abase, &sA[1][0][0], 0, 1);
  VM6();            // A(0),B(0) landed; {B(1)h0,h1, A(1)h0} in flight
  BAR();

  // operand register sets (ping-pong per kbuf); afL0/bf00 are loop-carried
  short8 afL0[4][2], afH0[4][2], bf00[2][2], bf10[2][2];
  short8 afL1[4][2], afH1[4][2], bf01[2][2], bf11[2][2];

  // pre-loop: reads for ph1's q1 (kbuf0: A m0-3, B n0-1)
  {
    const char* bA0 = (const char*)&sA[0][wm][0];
    const char* bB0 = (const char*)&sB[0][wn >> 1][0];
#pragma unroll
    for (int m = 0; m < 4; ++m)
#pragma unroll
      for (int kh = 0; kh < 2; ++kh) afL0[m][kh] = ARD(bA0, m, kh);
#pragma unroll
    for (int n = 0; n < 2; ++n)
#pragma unroll
      for (int kh = 0; kh < 2; ++kh) bf00[n][kh] = ARD(bB0, nsub + n, kh);
  }

#pragma unroll 1
  for (int i = 0; i < 32; ++i) {
    const int kt1 = 2 * i + 1;
    const int ktN0 = (2 * i + 2 < 64) ? 2 * i + 2 : 63;
    const int ktN1 = (2 * i + 3 < 64) ? 2 * i + 3 : 63;

    const char* bA0 = (const char*)&sA[0][wm][0];
    const char* bB0 = (const char*)&sB[0][wn >> 1][0];
    const char* bA1 = (const char*)&sA[1][wm][0];
    const char* bB1 = (const char*)&sB[1][wn >> 1][0];

    // -- ph1: reads bf10 (for q2); q1 = afL0 x bf00; stage A(kt1,h1) --
#pragma unroll
    for (int n = 0; n < 2; ++n)
#pragma unroll
      for (int kh = 0; kh < 2; ++kh) bf10[n][kh] = ARD(bB0, nsub + n + 2, kh);
    PRIO1();
#pragma unroll
    for (int m = 0; m < 4; ++m)
#pragma unroll
      for (int n = 0; n < 2; ++n)
#pragma unroll
        for (int kh = 0; kh < 2; ++kh)
          acc[m][n] = __builtin_amdgcn_mfma_f32_16x16x32_bf16(afL0[m][kh], bf00[n][kh], acc[m][n], 0, 0, 0);
    PRIO0();
    stage(Abase, &sA[1][1][0], 1, kt1);
    BAR();

    // -- ph2: reads afH0 (for q3); q2 = afL0 x bf10 --
#pragma unroll
    for (int m = 0; m < 4; ++m)
#pragma unroll
      for (int kh = 0; kh < 2; ++kh) afH0[m][kh] = ARD(bA0, m + 4, kh);
    PRIO1();
#pragma unroll
    for (int m = 0; m < 4; ++m)
#pragma unroll
      for (int n = 0; n < 2; ++n)
#pragma unroll
        for (int kh = 0; kh < 2; ++kh)
          acc[m][n + 2] = __builtin_amdgcn_mfma_f32_16x16x32_bf16(afL0[m][kh], bf10[n][kh], acc[m][n + 2], 0, 0, 0);
    PRIO0();
    BAR();

    // -- ph3: q3 = afH0 x bf10; stage B(ktN0,h0); VM2 -> kbuf1 landed --
    PRIO1();
#pragma unroll
    for (int m = 0; m < 4; ++m)
#pragma unroll
      for (int n = 0; n < 2; ++n)
#pragma unroll
        for (int kh = 0; kh < 2; ++kh)
          acc[m + 4][n + 2] = __builtin_amdgcn_mfma_f32_16x16x32_bf16(afH0[m][kh], bf10[n][kh], acc[m + 4][n + 2], 0, 0, 0);
    PRIO0();
    stage(Bbase, &sB[0][0][0], 0, ktN0);
    VM2();
    BAR();

    // -- ph4: reads afL1,bf01 (kbuf1, for q1'); q4 = afH0 x bf00;
    //         stage B(ktN0,h1) + A(ktN0,h0) --
#pragma unroll
    for (int m = 0; m < 4; ++m)
#pragma unroll
      for (int kh = 0; kh < 2; ++kh) afL1[m][kh] = ARD(bA1, m, kh);
#pragma unroll
    for (int n = 0; n < 2; ++n)
#pragma unroll
      for (int kh = 0; kh < 2; ++kh) bf01[n][kh] = ARD(bB1, nsub + n, kh);
    PRIO1();
#pragma unroll
    for (int m = 0; m < 4; ++m)
#pragma unroll
      for (int n = 0; n < 2; ++n)
#pragma unroll
        for (int kh = 0; kh < 2; ++kh)
          acc[m + 4][n] = __builtin_amdgcn_mfma_f32_16x16x32_bf16(afH0[m][kh], bf00[n][kh], acc[m + 4][n], 0, 0, 0);
    PRIO0();
    stage(Bbase, &sB[0][1][0], 1, ktN0);
    stage(Abase, &sA[0][0][0], 0, ktN0);
    BAR();

    // -- ph5: reads bf11 (for q2'); q1' = afL1 x bf01; stage A(ktN0,h1) --
#pragma unroll
    for (int n = 0; n < 2; ++n)
#pragma unroll
      for (int kh = 0; kh < 2; ++kh) bf11[n][kh] = ARD(bB1, nsub + n + 2, kh);
    PRIO1();
#pragma unroll
    for (int m = 0; m < 4; ++m)
#pragma unroll
      for (int n = 0; n < 2; ++n)
#pragma unroll
        for (int kh = 0; kh < 2; ++kh)
          acc[m][n] = __builtin_amdgcn_mfma_f32_16x16x32_bf16(afL1[m][kh], bf01[n][kh], acc[m][n], 0, 0, 0);
    PRIO0();
    stage(Abase, &sA[0][1][0], 1, ktN0);
    BAR();

    // -- ph6: reads afH1 (for q3'); q2' = afL1 x bf11 --
#pragma unroll
    for (int m = 0; m < 4; ++m)
#pragma unroll
      for (int kh = 0; kh < 2; ++kh) afH1[m][kh] = ARD(bA1, m + 4, kh);
    PRIO1();
#pragma unroll
    for (int m = 0; m < 4; ++m)
#pragma unroll
      for (int n = 0; n < 2; ++n)
#pragma unroll
        for (int kh = 0; kh < 2; ++kh)
          acc[m][n + 2] = __builtin_amdgcn_mfma_f32_16x16x32_bf16(afL1[m][kh], bf11[n][kh], acc[m][n + 2], 0, 0, 0);
    PRIO0();
    BAR();

    // -- ph7: q3' = afH1 x bf11; stage B(ktN1,h0); VM2 -> kbuf0(N0) landed --
    PRIO1();
#pragma unroll
    for (int m = 0; m < 4; ++m)
#pragma unroll
      for (int n = 0; n < 2; ++n)
#pragma unroll
        for (int kh = 0; kh < 2; ++kh)
          acc[m + 4][n + 2] = __builtin_amdgcn_mfma_f32_16x16x32_bf16(afH1[m][kh], bf11[n][kh], acc[m + 4][n + 2], 0, 0, 0);
    PRIO0();
    stage(Bbase, &sB[1][0][0], 0, ktN1);
    VM2();
    BAR();

    // -- ph8: reads afL0,bf00 (kbuf0 = ktN0 content, for next q1);
    //         q4' = afH1 x bf01; stage B(ktN1,h1) + A(ktN1,h0) --
#pragma unroll
    for (int m = 0; m < 4; ++m)
#pragma unroll
      for (int kh = 0; kh < 2; ++kh) afL0[m][kh] = ARD(bA0, m, kh);
#pragma unroll
    for (int n = 0; n < 2; ++n)
#pragma unroll
      for (int kh = 0; kh < 2; ++kh) bf00[n][kh] = ARD(bB0, nsub + n, kh);
    PRIO1();
#pragma unroll
    for (int m = 0; m < 4; ++m)
#pragma unroll
      for (int n = 0; n < 2; ++n)
#pragma unroll
        for (int kh = 0; kh < 2; ++kh)
          acc[m + 4][n] = __builtin_amdgcn_mfma_f32_16x16x32_bf16(afH1[m][kh], bf01[n][kh], acc[m + 4][n], 0, 0, 0);
    PRIO0();
    stage(Bbase, &sB[1][1][0], 1, ktN1);
    stage(Abase, &sA[1][0][0], 0, ktN1);
    BAR();
  }

  // ---- epilogue: drain tail stage loads (they write LDS async), then
  //      LDS-transposed vectorized C-write ----
  VM0();
  BAR();
  {
    // per-wave private slice: 32 rows x 272B (68 f32, padded) = 8704B
    char* sl = (wv < 4) ? ((char*)&sA[0][0][0] + wv * 8704)
                        : ((char*)&sB[0][0][0] + (wv - 4) * 8704);
    float* slf = (float*)sl;
    const int rb = brow * 256 + wm * 128;
    const int cb = bcol * 256 + wn * 64;
    const int rloc = lane >> 4;        // 0..3
    const int c4 = lane & 15;          // 0..15
#pragma unroll 1
    for (int mb = 0; mb < 4; ++mb) {
      // scatter acc quadrants (rows mb*32 .. mb*32+31) into padded LDS tile
#pragma unroll
      for (int mm = 0; mm < 2; ++mm)
#pragma unroll
        for (int n = 0; n < 4; ++n)
#pragma unroll
          for (int j = 0; j < 4; ++j)
            slf[(mm * 16 + fk * 4 + j) * 68 + n * 16 + fr] = acc[2 * mb + mm][n][j];
      // gather row-major, store 16B/lane (4x256B contiguous per wave-instr)
#pragma unroll
      for (int r = 0; r < 8; ++r) {
        f32x4 vv = *(const f32x4*)(sl + (r * 4 + rloc) * 272 + c4 * 16);
        *(f32x4*)(&C[(size_t)(rb + mb * 32 + r * 4 + rloc) * GK + cb + c4 * 4]) = vv;
      }
      LGKM0();   // all reads of this chunk complete before next chunk overwrites
    }
  }
}

// ---------------------------------------------------------------------------
extern "C" void kernel_launch(void* const* d_in, const int* in_sizes, int n_in,
                              void* d_out, int out_size, void* d_ws, size_t ws_size,
                              hipStream_t stream) {
  const float* x = (const float*)d_in[0];
  const float* W = (const float*)d_in[1];
  const float* lut = (const float*)d_in[2];
  float* out = (float*)d_out;

  unsigned short* xb = (unsigned short*)d_ws;                  // 32 MB bf16 x
  unsigned short* qb = xb + (size_t)4096 * 4096;               // 32 MB bf16 qweight

  prep_kernel<<<8192, 256, 0, stream>>>(x, W, lut, xb, qb);
  gemm_bt<<<256, 512, 0, stream>>>(xb, qb, out);
}

// Round 15
// 150.482 us; speedup vs baseline: 1.2740x; 1.2740x over previous
//
#include <hip/hip_runtime.h>
#include <hip/hip_fp16.h>
#include <stdint.h>

typedef __attribute__((ext_vector_type(4))) float f32x4;
typedef __attribute__((ext_vector_type(8))) short short8;

__device__ __forceinline__ unsigned short f2bf(float f) {
  unsigned int b = __float_as_uint(f);
  b = b + 0x7FFFu + ((b >> 16) & 1u);   // RNE
  return (unsigned short)(b >> 16);
}

#define CE(a, b) { float _lo = fminf((a), (b)), _hi = fmaxf((a), (b)); (a) = _lo; (b) = _hi; }

// Batcher odd-even merge of two ascending sorted 4-lists (x[0..3], x[4..7]) -> sorted 8
__device__ __forceinline__ void merge8(float x[8]) {
  CE(x[0], x[4]); CE(x[1], x[5]); CE(x[2], x[6]); CE(x[3], x[7]);
  CE(x[2], x[4]); CE(x[3], x[5]);
  CE(x[1], x[2]); CE(x[3], x[4]); CE(x[5], x[6]);
}

// ---------------------------------------------------------------------------
// Fused prep kernel: blocks 0..4095 = per-row NF4 quant+dequant of W -> qb,
//                    blocks 4096..8191 = x fp32 -> bf16 cvt
// ---------------------------------------------------------------------------
__global__ __launch_bounds__(256) void prep_kernel(const float* __restrict__ x,
                                                   const float* __restrict__ W,
                                                   const float* __restrict__ lut,
                                                   unsigned short* __restrict__ xb,
                                                   unsigned short* __restrict__ qb) {
  const int tid = threadIdx.x;

  if (blockIdx.x >= 4096) {
    // ---- cvt path ----
    int b = blockIdx.x - 4096;
    int base = b * 1024 + tid;   // float4 index
#pragma unroll
    for (int it = 0; it < 4; ++it) {
      int i = base + it * 256;
      f32x4 v = ((const f32x4*)x)[i];
      ushort4 u;
      u.x = f2bf(v[0]); u.y = f2bf(v[1]); u.z = f2bf(v[2]); u.w = f2bf(v[3]);
      ((ushort4*)xb)[i] = u;
    }
    return;
  }

  // ---- quant path ----
  const int C = 4096;
  const int row = blockIdx.x;
  const int lane = tid & 63;
  const int wv = tid >> 6;

  __shared__ float s_luth[16];   // fp16-rounded poles (dequant values)
  __shared__ float s_mid[15];    // decision midpoints on fp32 poles
  __shared__ float s_red[4][8];
  __shared__ float s_par[4];

  if (tid < 16) {
    float f = lut[tid];
    s_luth[tid] = __half2float(__float2half(f));  // .half() per reference
  }
  if (tid < 15) s_mid[tid] = 0.5f * (lut[tid] + lut[tid + 1]);

  const f32x4* Wp = (const f32x4*)(W + (size_t)row * C);
  f32x4 v[4];
#pragma unroll
  for (int i = 0; i < 4; ++i) v[i] = Wp[i * 256 + tid];

  // per-thread bottom-4 (ascending) and top-4 (ascending)
  float bot[4] = {__builtin_inff(), __builtin_inff(), __builtin_inff(), __builtin_inff()};
  float top[4] = {-__builtin_inff(), -__builtin_inff(), -__builtin_inff(), -__builtin_inff()};
#pragma unroll
  for (int i = 0; i < 4; ++i) {
#pragma unroll
    for (int j = 0; j < 4; ++j) {
      float f = v[i][j];
      bot[3] = fminf(bot[3], f); CE(bot[2], bot[3]); CE(bot[1], bot[2]); CE(bot[0], bot[1]);
      top[0] = fmaxf(top[0], f); CE(top[0], top[1]); CE(top[1], top[2]); CE(top[2], top[3]);
    }
  }

#pragma unroll
  for (int d = 1; d < 64; d <<= 1) {
    float xx[8];
#pragma unroll
    for (int j = 0; j < 4; ++j) { xx[j] = bot[j]; xx[4 + j] = __shfl_xor(bot[j], d); }
    merge8(xx);
#pragma unroll
    for (int j = 0; j < 4; ++j) bot[j] = xx[j];
#pragma unroll
    for (int j = 0; j < 4; ++j) { xx[j] = top[j]; xx[4 + j] = __shfl_xor(top[j], d); }
    merge8(xx);
#pragma unroll
    for (int j = 0; j < 4; ++j) top[j] = xx[4 + j];
  }

  if (lane == 0) {
#pragma unroll
    for (int j = 0; j < 4; ++j) { s_red[wv][j] = bot[j]; s_red[wv][4 + j] = top[j]; }
  }
  __syncthreads();

  if (tid == 0) {
    float a[8], b[8], m[8];
#pragma unroll
    for (int j = 0; j < 4; ++j) { a[j] = s_red[0][j]; a[4 + j] = s_red[1][j]; }
    merge8(a);
#pragma unroll
    for (int j = 0; j < 4; ++j) { b[j] = s_red[2][j]; b[4 + j] = s_red[3][j]; }
    merge8(b);
#pragma unroll
    for (int j = 0; j < 4; ++j) { m[j] = a[j]; m[4 + j] = b[j]; }
    merge8(m);
    float lower = m[2] + 0.0475f * (m[3] - m[2]);   // quantile 0.0005 -> idx 2.0475
#pragma unroll
    for (int j = 0; j < 4; ++j) { a[j] = s_red[0][4 + j]; a[4 + j] = s_red[1][4 + j]; }
    merge8(a);
#pragma unroll
    for (int j = 0; j < 4; ++j) { b[j] = s_red[2][4 + j]; b[4 + j] = s_red[3][4 + j]; }
    merge8(b);
#pragma unroll
    for (int j = 0; j < 4; ++j) { m[j] = a[4 + j]; m[4 + j] = b[4 + j]; }
    merge8(m);
    float upper = m[4] + 0.9525f * (m[5] - m[4]);   // quantile 0.9995 -> idx 4092.9525
    s_par[0] = lower; s_par[1] = upper;
  }
  __syncthreads();

  float lower = s_par[0], upper = s_par[1];

  float mn = __builtin_inff(), mx = -__builtin_inff();
#pragma unroll
  for (int i = 0; i < 4; ++i) {
#pragma unroll
    for (int j = 0; j < 4; ++j) {
      float f = v[i][j];
      bool outl = (f <= lower) || (f >= upper);
      if (!outl) { mn = fminf(mn, f); mx = fmaxf(mx, f); }
    }
  }
#pragma unroll
  for (int d = 1; d < 64; d <<= 1) {
    mn = fminf(mn, __shfl_xor(mn, d));
    mx = fmaxf(mx, __shfl_xor(mx, d));
  }
  if (lane == 0) { s_red[wv][0] = mn; s_red[wv][1] = mx; }
  __syncthreads();
  if (tid == 0) {
    float tmn = fminf(fminf(s_red[0][0], s_red[1][0]), fminf(s_red[2][0], s_red[3][0]));
    float tmx = fmaxf(fmaxf(s_red[0][1], s_red[1][1]), fmaxf(s_red[2][1], s_red[3][1]));
    s_par[2] = (tmx + tmn) * 0.5f;   // offset
    s_par[3] = (tmx - tmn) * 0.5f;   // rangeval
  }
  __syncthreads();
  float offset = s_par[2], range = s_par[3];
  float invr = 1.0f / range;

  unsigned short* outr = qb + (size_t)row * C;
#pragma unroll
  for (int i = 0; i < 4; ++i) {
    ushort4 o;
    unsigned short os[4];
#pragma unroll
    for (int j = 0; j < 4; ++j) {
      float f = v[i][j];
      bool outl = (f <= lower) || (f >= upper);
      float q;
      if (outl) {
        q = f;  // Q=0 pole -> weight passes through
      } else {
        // nearest pole via branchless binary search on midpoints.
        // strict '>' keeps the LOWER index on exact ties == argmin semantics.
        float ws = (f - offset) * invr;
        int bi = (ws > s_mid[7]) ? 8 : 0;
        bi += (ws > s_mid[bi + 3]) ? 4 : 0;
        bi += (ws > s_mid[bi + 1]) ? 2 : 0;
        bi += (ws > s_mid[bi]) ? 1 : 0;
        q = s_luth[bi] * range + offset;
      }
      if (!isfinite(q)) q = 0.0f;
      os[j] = f2bf(q);
    }
    o.x = os[0]; o.y = os[1]; o.z = os[2]; o.w = os[3];
    ((ushort4*)outr)[i * 256 + tid] = o;
  }
}

// ---------------------------------------------------------------------------
// GEMM (FINAL = round 11/13, the measured optimum: gemm 114.3us, MfmaUtil 54%,
// conflicts 0): one-phase-early operand pipeline on the 8-phase skeleton.
// Each phase p: {issue ds_reads for phase p+1} -> {MFMA p (operands read in
// p-1; counted lgkm wait skips the new reads)} -> {stage} -> [VM] -> BAR.
// Waits: VM2 end-ph3/end-ph7 (counted, never 0 in loop). Scalar C-write
// epilogue KEPT: R14's LDS-transposed dwordx4 variant caused 3x HBM write
// amplification (WRITE 65.5->200.7 MB) and +56us -- do not reintroduce.
// ---------------------------------------------------------------------------
#define GK 4096

__device__ __forceinline__ void gload16(const void* gp, void* lp) {
  __builtin_amdgcn_global_load_lds(
      (const __attribute__((address_space(1))) unsigned int*)(uintptr_t)gp,
      (__attribute__((address_space(3))) unsigned int*)(unsigned int)(uintptr_t)lp,
      16, 0, 0);
}

#define BAR()    __builtin_amdgcn_s_barrier()
#define VM2()    asm volatile("s_waitcnt vmcnt(2)" ::: "memory")
#define VM6()    asm volatile("s_waitcnt vmcnt(6)" ::: "memory")
#define PRIO1()  __builtin_amdgcn_s_setprio(1)
#define PRIO0()  __builtin_amdgcn_s_setprio(0)

// frag-read address helper (subtiled st_16x32 layout, conflicts==0)
#define ARD(buf, m, kh)  (*(const short8*)((buf) + (m) * 2048 + (kh) * 1024 + fr * 64 + cA))

__global__ __launch_bounds__(512, 2) void gemm_bt(const unsigned short* __restrict__ A,
                                                  const unsigned short* __restrict__ B,
                                                  float* __restrict__ C) {
  // [kbuf][half][16KB half-tile] ; total 128 KiB
  __shared__ __align__(16) unsigned short sA[2][2][8192];
  __shared__ __align__(16) unsigned short sB[2][2][8192];

  const int tid = threadIdx.x;
  const int lane = tid & 63;
  const int wv = tid >> 6;
  const int wm = wv >> 2, wn = wv & 3;       // 2 x 4 wave grid; wave tile 128 x 64
  const int fr = lane & 15, fk = lane >> 4;

  // XCD-aware swizzle: 256 blocks, 256 % 8 == 0 -> bijective
  int bi = blockIdx.x;
  int swz = (bi & 7) * 32 + (bi >> 3);
  int brow = swz >> 4, bcol = swz & 15;

  const unsigned short* Abase = A + (size_t)brow * 256 * GK;
  const unsigned short* Bbase = B + (size_t)bcol * 256 * GK;

  // read-side swizzled column byte within 64B row: fk*16 ^ (row-bit-3 << 5)
  const int cA = (fk * 16) ^ ((fr & 8) << 2);

  // stage source permutation (verified bijective): LDS bytes [wv*1024+l*8192+lane*16)
  // hold global (row = l*64 + (wv>>1)*16 + (lane>>2),
  //              kbyte = (wv&1)*64 + ((lane&3)*16 ^ (lane&32 ? 32 : 0)))
  const int srow = (wv >> 1) * 16 + (lane >> 2);                 // + l*64
  const int skelt = ((wv & 1) * 64 + (((lane & 3) * 16) ^ ((lane & 32) ? 32 : 0))) >> 1;

  auto stage = [&](const unsigned short* gb, unsigned short* lb, int h, int kt) {
    const unsigned short* g = gb + ((size_t)h * 128) * GK + kt * 64 + skelt;
    char* lc = (char*)lb + wv * 1024 + lane * 16;
#pragma unroll
    for (int l = 0; l < 2; ++l)
      gload16(g + (size_t)(l * 64 + srow) * GK, lc + l * 8192);
  };

  f32x4 acc[8][4];
#pragma unroll
  for (int m = 0; m < 8; ++m)
#pragma unroll
    for (int n = 0; n < 4; ++n) acc[m][n] = (f32x4){0.f, 0.f, 0.f, 0.f};

  const int nsub = (wn & 1) * 4;       // B subtile-row base within half

  // ---- prologue: A(0)h0,h1, B(0)h0,h1 [kbuf0] + B(1)h0,h1, A(1)h0 [kbuf1]
  stage(Abase, &sA[0][0][0], 0, 0);
  stage(Abase, &sA[0][1][0], 1, 0);
  stage(Bbase, &sB[0][0][0], 0, 0);
  stage(Bbase, &sB[0][1][0], 1, 0);
  stage(Bbase, &sB[1][0][0], 0, 1);
  stage(Bbase, &sB[1][1][0], 1, 1);
  stage(Abase, &sA[1][0][0], 0, 1);
  VM6();            // A(0),B(0) landed; {B(1)h0,h1, A(1)h0} in flight
  BAR();

  // operand register sets (ping-pong per kbuf); afL0/bf00 are loop-carried
  short8 afL0[4][2], afH0[4][2], bf00[2][2], bf10[2][2];
  short8 afL1[4][2], afH1[4][2], bf01[2][2], bf11[2][2];

  // pre-loop: reads for ph1's q1 (kbuf0: A m0-3, B n0-1)
  {
    const char* bA0 = (const char*)&sA[0][wm][0];
    const char* bB0 = (const char*)&sB[0][wn >> 1][0];
#pragma unroll
    for (int m = 0; m < 4; ++m)
#pragma unroll
      for (int kh = 0; kh < 2; ++kh) afL0[m][kh] = ARD(bA0, m, kh);
#pragma unroll
    for (int n = 0; n < 2; ++n)
#pragma unroll
      for (int kh = 0; kh < 2; ++kh) bf00[n][kh] = ARD(bB0, nsub + n, kh);
  }

#pragma unroll 1
  for (int i = 0; i < 32; ++i) {
    const int kt1 = 2 * i + 1;
    const int ktN0 = (2 * i + 2 < 64) ? 2 * i + 2 : 63;
    const int ktN1 = (2 * i + 3 < 64) ? 2 * i + 3 : 63;

    const char* bA0 = (const char*)&sA[0][wm][0];
    const char* bB0 = (const char*)&sB[0][wn >> 1][0];
    const char* bA1 = (const char*)&sA[1][wm][0];
    const char* bB1 = (const char*)&sB[1][wn >> 1][0];

    // -- ph1: reads bf10 (for q2); q1 = afL0 x bf00; stage A(kt1,h1) --
#pragma unroll
    for (int n = 0; n < 2; ++n)
#pragma unroll
      for (int kh = 0; kh < 2; ++kh) bf10[n][kh] = ARD(bB0, nsub + n + 2, kh);
    PRIO1();
#pragma unroll
    for (int m = 0; m < 4; ++m)
#pragma unroll
      for (int n = 0; n < 2; ++n)
#pragma unroll
        for (int kh = 0; kh < 2; ++kh)
          acc[m][n] = __builtin_amdgcn_mfma_f32_16x16x32_bf16(afL0[m][kh], bf00[n][kh], acc[m][n], 0, 0, 0);
    PRIO0();
    stage(Abase, &sA[1][1][0], 1, kt1);
    BAR();

    // -- ph2: reads afH0 (for q3); q2 = afL0 x bf10 --
#pragma unroll
    for (int m = 0; m < 4; ++m)
#pragma unroll
      for (int kh = 0; kh < 2; ++kh) afH0[m][kh] = ARD(bA0, m + 4, kh);
    PRIO1();
#pragma unroll
    for (int m = 0; m < 4; ++m)
#pragma unroll
      for (int n = 0; n < 2; ++n)
#pragma unroll
        for (int kh = 0; kh < 2; ++kh)
          acc[m][n + 2] = __builtin_amdgcn_mfma_f32_16x16x32_bf16(afL0[m][kh], bf10[n][kh], acc[m][n + 2], 0, 0, 0);
    PRIO0();
    BAR();

    // -- ph3: q3 = afH0 x bf10; stage B(ktN0,h0); VM2 -> kbuf1 landed --
    PRIO1();
#pragma unroll
    for (int m = 0; m < 4; ++m)
#pragma unroll
      for (int n = 0; n < 2; ++n)
#pragma unroll
        for (int kh = 0; kh < 2; ++kh)
          acc[m + 4][n + 2] = __builtin_amdgcn_mfma_f32_16x16x32_bf16(afH0[m][kh], bf10[n][kh], acc[m + 4][n + 2], 0, 0, 0);
    PRIO0();
    stage(Bbase, &sB[0][0][0], 0, ktN0);
    VM2();
    BAR();

    // -- ph4: reads afL1,bf01 (kbuf1, for q1'); q4 = afH0 x bf00;
    //         stage B(ktN0,h1) + A(ktN0,h0) --
#pragma unroll
    for (int m = 0; m < 4; ++m)
#pragma unroll
      for (int kh = 0; kh < 2; ++kh) afL1[m][kh] = ARD(bA1, m, kh);
#pragma unroll
    for (int n = 0; n < 2; ++n)
#pragma unroll
      for (int kh = 0; kh < 2; ++kh) bf01[n][kh] = ARD(bB1, nsub + n, kh);
    PRIO1();
#pragma unroll
    for (int m = 0; m < 4; ++m)
#pragma unroll
      for (int n = 0; n < 2; ++n)
#pragma unroll
        for (int kh = 0; kh < 2; ++kh)
          acc[m + 4][n] = __builtin_amdgcn_mfma_f32_16x16x32_bf16(afH0[m][kh], bf00[n][kh], acc[m + 4][n], 0, 0, 0);
    PRIO0();
    stage(Bbase, &sB[0][1][0], 1, ktN0);
    stage(Abase, &sA[0][0][0], 0, ktN0);
    BAR();

    // -- ph5: reads bf11 (for q2'); q1' = afL1 x bf01; stage A(ktN0,h1) --
#pragma unroll
    for (int n = 0; n < 2; ++n)
#pragma unroll
      for (int kh = 0; kh < 2; ++kh) bf11[n][kh] = ARD(bB1, nsub + n + 2, kh);
    PRIO1();
#pragma unroll
    for (int m = 0; m < 4; ++m)
#pragma unroll
      for (int n = 0; n < 2; ++n)
#pragma unroll
        for (int kh = 0; kh < 2; ++kh)
          acc[m][n] = __builtin_amdgcn_mfma_f32_16x16x32_bf16(afL1[m][kh], bf01[n][kh], acc[m][n], 0, 0, 0);
    PRIO0();
    stage(Abase, &sA[0][1][0], 1, ktN0);
    BAR();

    // -- ph6: reads afH1 (for q3'); q2' = afL1 x bf11 --
#pragma unroll
    for (int m = 0; m < 4; ++m)
#pragma unroll
      for (int kh = 0; kh < 2; ++kh) afH1[m][kh] = ARD(bA1, m + 4, kh);
    PRIO1();
#pragma unroll
    for (int m = 0; m < 4; ++m)
#pragma unroll
      for (int n = 0; n < 2; ++n)
#pragma unroll
        for (int kh = 0; kh < 2; ++kh)
          acc[m][n + 2] = __builtin_amdgcn_mfma_f32_16x16x32_bf16(afL1[m][kh], bf11[n][kh], acc[m][n + 2], 0, 0, 0);
    PRIO0();
    BAR();

    // -- ph7: q3' = afH1 x bf11; stage B(ktN1,h0); VM2 -> kbuf0(N0) landed --
    PRIO1();
#pragma unroll
    for (int m = 0; m < 4; ++m)
#pragma unroll
      for (int n = 0; n < 2; ++n)
#pragma unroll
        for (int kh = 0; kh < 2; ++kh)
          acc[m + 4][n + 2] = __builtin_amdgcn_mfma_f32_16x16x32_bf16(afH1[m][kh], bf11[n][kh], acc[m + 4][n + 2], 0, 0, 0);
    PRIO0();
    stage(Bbase, &sB[1][0][0], 0, ktN1);
    VM2();
    BAR();

    // -- ph8: reads afL0,bf00 (kbuf0 = ktN0 content, for next q1);
    //         q4' = afH1 x bf01; stage B(ktN1,h1) + A(ktN1,h0) --
#pragma unroll
    for (int m = 0; m < 4; ++m)
#pragma unroll
      for (int kh = 0; kh < 2; ++kh) afL0[m][kh] = ARD(bA0, m, kh);
#pragma unroll
    for (int n = 0; n < 2; ++n)
#pragma unroll
      for (int kh = 0; kh < 2; ++kh) bf00[n][kh] = ARD(bB0, nsub + n, kh);
    PRIO1();
#pragma unroll
    for (int m = 0; m < 4; ++m)
#pragma unroll
      for (int n = 0; n < 2; ++n)
#pragma unroll
        for (int kh = 0; kh < 2; ++kh)
          acc[m + 4][n] = __builtin_amdgcn_mfma_f32_16x16x32_bf16(afH1[m][kh], bf01[n][kh], acc[m + 4][n], 0, 0, 0);
    PRIO0();
    stage(Bbase, &sB[1][1][0], 1, ktN1);
    stage(Abase, &sA[1][0][0], 0, ktN1);
    BAR();
  }

  // epilogue: verified C/D mapping: row = m*16 + fk*4 + j, col = n*16 + fr
  const int rbase = brow * 256 + wm * 128;
  const int cbase = bcol * 256 + wn * 64;
#pragma unroll
  for (int m = 0; m < 8; ++m)
#pragma unroll
    for (int n = 0; n < 4; ++n)
#pragma unroll
      for (int j = 0; j < 4; ++j) {
        int rr = rbase + m * 16 + fk * 4 + j;
        int cc = cbase + n * 16 + fr;
        C[(size_t)rr * GK + cc] = acc[m][n][j];
      }
}

// ---------------------------------------------------------------------------
extern "C" void kernel_launch(void* const* d_in, const int* in_sizes, int n_in,
                              void* d_out, int out_size, void* d_ws, size_t ws_size,
                              hipStream_t stream) {
  const float* x = (const float*)d_in[0];
  const float* W = (const float*)d_in[1];
  const float* lut = (const float*)d_in[2];
  float* out = (float*)d_out;

  unsigned short* xb = (unsigned short*)d_ws;                  // 32 MB bf16 x
  unsigned short* qb = xb + (size_t)4096 * 4096;               // 32 MB bf16 qweight

  prep_kernel<<<8192, 256, 0, stream>>>(x, W, lut, xb, qb);
  gemm_bt<<<256, 512, 0, stream>>>(xb, qb, out);
}